// Round 1
// baseline (289.287 us; speedup 1.0000x reference)
//
#include <hip/hip_runtime.h>

// Problem constants (from reference setup_inputs): N=32768, n_classes=1000, embed=1024
constexpr int N_CLASSES = 1000;
constexpr int EMBED     = 1024;
constexpr int ROWS_PER_BLOCK = 8;

// One block of 256 threads processes ROWS_PER_BLOCK rows.
// Per row:
//   Phase A: recover one-hot index via y = sum_c c*label[c] (exact in fp32, y<1000<2^24)
//   Phase B: f.f, p.p, f.p dot products with float4 loads, wave+LDS reduction
// Per-block partial sum of (1-cos) goes to d_ws; a second tiny kernel reduces.
__global__ __launch_bounds__(256) void angular_rows_kernel(
    const float* __restrict__ features,
    const float* __restrict__ labels,
    const float* __restrict__ mean_class,
    float* __restrict__ partials,
    int n_rows)
{
    const int tid  = threadIdx.x;
    const int lane = tid & 63;
    const int wave = tid >> 6;

    __shared__ float s_a[4], s_b[4], s_c[4];
    __shared__ int   s_idx;

    float block_acc = 0.0f;

    for (int r = 0; r < ROWS_PER_BLOCK; ++r) {
        const int row = blockIdx.x * ROWS_PER_BLOCK + r;
        if (row >= n_rows) break;

        // Feature fragment load (independent of label scan -> overlaps latency)
        const float4 f = ((const float4*)(features + (size_t)row * EMBED))[tid];

        // --- Phase A: one-hot index. 250 float4 cover the 1000-class row. ---
        float idxf = 0.0f;
        if (tid < N_CLASSES / 4) {
            const float4 v = ((const float4*)(labels + (size_t)row * N_CLASSES))[tid];
            const float c = (float)(tid * 4);
            idxf = v.x * c + v.y * (c + 1.0f) + v.z * (c + 2.0f) + v.w * (c + 3.0f);
        }
        #pragma unroll
        for (int off = 32; off > 0; off >>= 1)
            idxf += __shfl_down(idxf, off, 64);
        if (lane == 0) s_a[wave] = idxf;
        __syncthreads();
        if (tid == 0) s_idx = (int)(s_a[0] + s_a[1] + s_a[2] + s_a[3] + 0.5f);
        __syncthreads();
        const int cls = s_idx;

        // --- Phase B: prototype gather + three dots ---
        const float4 p = ((const float4*)(mean_class + (size_t)cls * EMBED))[tid];

        float ff = f.x*f.x + f.y*f.y + f.z*f.z + f.w*f.w;
        float pp = p.x*p.x + p.y*p.y + p.z*p.z + p.w*p.w;
        float fp = f.x*p.x + f.y*p.y + f.z*p.z + f.w*p.w;
        #pragma unroll
        for (int off = 32; off > 0; off >>= 1) {
            ff += __shfl_down(ff, off, 64);
            pp += __shfl_down(pp, off, 64);
            fp += __shfl_down(fp, off, 64);
        }
        if (lane == 0) { s_a[wave] = ff; s_b[wave] = pp; s_c[wave] = fp; }
        __syncthreads();
        if (tid == 0) {
            const float FF = s_a[0] + s_a[1] + s_a[2] + s_a[3];
            const float PP = s_b[0] + s_b[1] + s_b[2] + s_b[3];
            const float FP = s_c[0] + s_c[1] + s_c[2] + s_c[3];
            const float denom = fmaxf(sqrtf(FF), 1e-12f) * fmaxf(sqrtf(PP), 1e-12f);
            block_acc += 1.0f - FP / denom;
        }
        __syncthreads();  // protect s_a/s_idx reuse in next iteration
    }

    if (tid == 0) partials[blockIdx.x] = block_acc;
}

__global__ __launch_bounds__(256) void reduce_partials_kernel(
    const float* __restrict__ partials, int num_partials,
    float* __restrict__ out, float inv_n)
{
    const int tid  = threadIdx.x;
    const int lane = tid & 63;
    const int wave = tid >> 6;
    __shared__ float s_red[4];

    float acc = 0.0f;
    for (int i = tid; i < num_partials; i += 256)
        acc += partials[i];
    #pragma unroll
    for (int off = 32; off > 0; off >>= 1)
        acc += __shfl_down(acc, off, 64);
    if (lane == 0) s_red[wave] = acc;
    __syncthreads();
    if (tid == 0)
        out[0] = (s_red[0] + s_red[1] + s_red[2] + s_red[3]) * inv_n;
}

extern "C" void kernel_launch(void* const* d_in, const int* in_sizes, int n_in,
                              void* d_out, int out_size, void* d_ws, size_t ws_size,
                              hipStream_t stream) {
    const float* features   = (const float*)d_in[0];
    const float* labels     = (const float*)d_in[1];
    const float* mean_class = (const float*)d_in[2];
    float* out = (float*)d_out;
    float* partials = (float*)d_ws;

    const int n_rows = in_sizes[0] / EMBED;           // 32768
    const int num_blocks = (n_rows + ROWS_PER_BLOCK - 1) / ROWS_PER_BLOCK;  // 4096 -> 16 KB ws

    angular_rows_kernel<<<num_blocks, 256, 0, stream>>>(
        features, labels, mean_class, partials, n_rows);
    reduce_partials_kernel<<<1, 256, 0, stream>>>(
        partials, num_blocks, out, 1.0f / (float)n_rows);
}

// Round 2
// 278.167 us; speedup vs baseline: 1.0400x; 1.0400x over previous
//
#include <hip/hip_runtime.h>

constexpr int N_CLASSES = 1000;   // 250 float4 per label row
constexpr int EMBED     = 1024;   // 256 float4 per feature/proto row; 4 float4 per lane

// One 64-lane wave per row, grid-stride over rows. No __syncthreads in the hot
// loop; all reductions are shfl_xor butterflies. Per-wave accumulator of
// (1 - cos) is combined per-block via LDS once at the end -> partials[block].
__global__ __launch_bounds__(256) void angular_rows_kernel(
    const float* __restrict__ features,
    const float* __restrict__ labels,
    const float* __restrict__ mean_class,
    float* __restrict__ partials,
    int n_rows)
{
    const int tid  = threadIdx.x;
    const int lane = tid & 63;
    const int wave = tid >> 6;

    const int wave_id = (blockIdx.x * blockDim.x + tid) >> 6;
    const int n_waves = (gridDim.x * blockDim.x) >> 6;

    float wave_acc = 0.0f;   // meaningful on lane 0 after final butterfly

    for (int row = wave_id; row < n_rows; row += n_waves) {
        // --- Issue all independent loads up front (8 in flight) ---
        const float4* frow = (const float4*)(features + (size_t)row * EMBED);
        float4 f0 = frow[lane];
        float4 f1 = frow[lane + 64];
        float4 f2 = frow[lane + 128];
        float4 f3 = frow[lane + 192];

        const float4* lrow = (const float4*)(labels + (size_t)row * N_CLASSES);
        float4 l0 = lrow[lane];
        float4 l1 = lrow[lane + 64];
        float4 l2 = lrow[lane + 128];
        float4 l3 = (lane < N_CLASSES / 4 - 192) ? lrow[lane + 192]
                                                 : make_float4(0, 0, 0, 0);

        // --- One-hot index: y = sum_c c * label[c] (exact in fp32, y < 1000) ---
        float idxf = 0.0f;
        {
            float c0 = (float)(lane * 4);
            idxf += l0.x * c0 + l0.y * (c0 + 1.f) + l0.z * (c0 + 2.f) + l0.w * (c0 + 3.f);
            float c1 = (float)((lane + 64) * 4);
            idxf += l1.x * c1 + l1.y * (c1 + 1.f) + l1.z * (c1 + 2.f) + l1.w * (c1 + 3.f);
            float c2 = (float)((lane + 128) * 4);
            idxf += l2.x * c2 + l2.y * (c2 + 1.f) + l2.z * (c2 + 2.f) + l2.w * (c2 + 3.f);
            float c3 = (float)((lane + 192) * 4);
            idxf += l3.x * c3 + l3.y * (c3 + 1.f) + l3.z * (c3 + 2.f) + l3.w * (c3 + 3.f);
        }
        #pragma unroll
        for (int m = 1; m < 64; m <<= 1)
            idxf += __shfl_xor(idxf, m, 64);          // all lanes get the sum
        const int cls = (int)(idxf + 0.5f);

        // --- Prototype gather + three dots ---
        const float4* prow = (const float4*)(mean_class + (size_t)cls * EMBED);
        float4 p0 = prow[lane];
        float4 p1 = prow[lane + 64];
        float4 p2 = prow[lane + 128];
        float4 p3 = prow[lane + 192];

        float ff = 0.f, pp = 0.f, fp = 0.f;
        #define DOT3(F, P) \
            ff += F.x*F.x + F.y*F.y + F.z*F.z + F.w*F.w; \
            pp += P.x*P.x + P.y*P.y + P.z*P.z + P.w*P.w; \
            fp += F.x*P.x + F.y*P.y + F.z*P.z + F.w*P.w;
        DOT3(f0, p0) DOT3(f1, p1) DOT3(f2, p2) DOT3(f3, p3)
        #undef DOT3

        #pragma unroll
        for (int m = 1; m < 64; m <<= 1) {
            ff += __shfl_xor(ff, m, 64);
            pp += __shfl_xor(pp, m, 64);
            fp += __shfl_xor(fp, m, 64);
        }
        const float denom = fmaxf(sqrtf(ff), 1e-12f) * fmaxf(sqrtf(pp), 1e-12f);
        wave_acc += 1.0f - fp / denom;                // identical on all lanes
    }

    // --- One block reduce at the very end ---
    __shared__ float s_red[4];
    if (lane == 0) s_red[wave] = wave_acc;
    __syncthreads();
    if (tid == 0)
        partials[blockIdx.x] = s_red[0] + s_red[1] + s_red[2] + s_red[3];
}

__global__ __launch_bounds__(256) void reduce_partials_kernel(
    const float* __restrict__ partials, int num_partials,
    float* __restrict__ out, float inv_n)
{
    const int tid  = threadIdx.x;
    const int lane = tid & 63;
    const int wave = tid >> 6;
    __shared__ float s_red[4];

    float acc = 0.0f;
    for (int i = tid; i < num_partials; i += 256)
        acc += partials[i];
    #pragma unroll
    for (int m = 1; m < 64; m <<= 1)
        acc += __shfl_xor(acc, m, 64);
    if (lane == 0) s_red[wave] = acc;
    __syncthreads();
    if (tid == 0)
        out[0] = (s_red[0] + s_red[1] + s_red[2] + s_red[3]) * inv_n;
}

extern "C" void kernel_launch(void* const* d_in, const int* in_sizes, int n_in,
                              void* d_out, int out_size, void* d_ws, size_t ws_size,
                              hipStream_t stream) {
    const float* features   = (const float*)d_in[0];
    const float* labels     = (const float*)d_in[1];
    const float* mean_class = (const float*)d_in[2];
    float* out = (float*)d_out;
    float* partials = (float*)d_ws;

    const int n_rows = in_sizes[0] / EMBED;   // 32768
    const int num_blocks = 1024;              // 4096 waves -> 8 rows per wave

    angular_rows_kernel<<<num_blocks, 256, 0, stream>>>(
        features, labels, mean_class, partials, n_rows);
    reduce_partials_kernel<<<1, 256, 0, stream>>>(
        partials, num_blocks, out, 1.0f / (float)n_rows);
}

// Round 4
// 260.497 us; speedup vs baseline: 1.1105x; 1.0678x over previous
//
#include <hip/hip_runtime.h>

constexpr int N_CLASSES = 1000;   // 250 float4 per label row
constexpr int EMBED     = 1024;   // 256 float4 per row; 4 float4 per lane

typedef float floatx4 __attribute__((ext_vector_type(4)));  // native vec for nontemporal builtin

// One 64-lane wave per row (8192 blocks x 4 waves = 32768 waves, no loop).
// Index extraction via ballot (short chain); streamed inputs use
// non-temporal loads to keep mean_class L2-resident.
__global__ __launch_bounds__(256) void angular_rows_kernel(
    const float* __restrict__ features,
    const float* __restrict__ labels,
    const float* __restrict__ mean_class,
    float* __restrict__ partials,
    int n_rows)
{
    const int tid  = threadIdx.x;
    const int lane = tid & 63;
    const int wave = tid >> 6;
    const int row  = blockIdx.x * 4 + wave;

    float res = 0.0f;

    if (row < n_rows) {
        // --- Issue all streaming loads up front (8 in flight) ---
        const floatx4* frow = (const floatx4*)(features + (size_t)row * EMBED);
        floatx4 f0 = __builtin_nontemporal_load(frow + lane);
        floatx4 f1 = __builtin_nontemporal_load(frow + lane + 64);
        floatx4 f2 = __builtin_nontemporal_load(frow + lane + 128);
        floatx4 f3 = __builtin_nontemporal_load(frow + lane + 192);

        const floatx4* lrow = (const floatx4*)(labels + (size_t)row * N_CLASSES);
        floatx4 l0 = __builtin_nontemporal_load(lrow + lane);
        floatx4 l1 = __builtin_nontemporal_load(lrow + lane + 64);
        floatx4 l2 = __builtin_nontemporal_load(lrow + lane + 128);
        floatx4 l3 = (lane < N_CLASSES / 4 - 192)
                         ? __builtin_nontemporal_load(lrow + lane + 192)
                         : (floatx4){0.f, 0.f, 0.f, 0.f};

        // --- One-hot index via ballot: 16 compares, one broadcast ---
        int cand = -1;
        if (l0.x != 0.f) cand = 4 * lane + 0;
        if (l0.y != 0.f) cand = 4 * lane + 1;
        if (l0.z != 0.f) cand = 4 * lane + 2;
        if (l0.w != 0.f) cand = 4 * lane + 3;
        if (l1.x != 0.f) cand = 4 * (lane + 64) + 0;
        if (l1.y != 0.f) cand = 4 * (lane + 64) + 1;
        if (l1.z != 0.f) cand = 4 * (lane + 64) + 2;
        if (l1.w != 0.f) cand = 4 * (lane + 64) + 3;
        if (l2.x != 0.f) cand = 4 * (lane + 128) + 0;
        if (l2.y != 0.f) cand = 4 * (lane + 128) + 1;
        if (l2.z != 0.f) cand = 4 * (lane + 128) + 2;
        if (l2.w != 0.f) cand = 4 * (lane + 128) + 3;
        if (l3.x != 0.f) cand = 4 * (lane + 192) + 0;
        if (l3.y != 0.f) cand = 4 * (lane + 192) + 1;
        if (l3.z != 0.f) cand = 4 * (lane + 192) + 2;
        if (l3.w != 0.f) cand = 4 * (lane + 192) + 3;

        unsigned long long m = __ballot(cand >= 0);
        int src = __ffsll((unsigned long long)m) - 1;
        int cls = __shfl(cand, src, 64);
        cls = __builtin_amdgcn_readfirstlane(cls);   // force scalar base

        // --- Prototype gather (cached) + three dots ---
        const floatx4* prow = (const floatx4*)(mean_class + (size_t)cls * EMBED);
        floatx4 p0 = prow[lane];
        floatx4 p1 = prow[lane + 64];
        floatx4 p2 = prow[lane + 128];
        floatx4 p3 = prow[lane + 192];

        float ff = 0.f, pp = 0.f, fp = 0.f;
        #define DOT3(F, P) \
            ff += F.x*F.x + F.y*F.y + F.z*F.z + F.w*F.w; \
            pp += P.x*P.x + P.y*P.y + P.z*P.z + P.w*P.w; \
            fp += F.x*P.x + F.y*P.y + F.z*P.z + F.w*P.w;
        DOT3(f0, p0) DOT3(f1, p1) DOT3(f2, p2) DOT3(f3, p3)
        #undef DOT3

        #pragma unroll
        for (int msk = 1; msk < 64; msk <<= 1) {
            ff += __shfl_xor(ff, msk, 64);
            pp += __shfl_xor(pp, msk, 64);
            fp += __shfl_xor(fp, msk, 64);
        }
        const float denom = fmaxf(sqrtf(ff), 1e-12f) * fmaxf(sqrtf(pp), 1e-12f);
        res = 1.0f - fp / denom;
    }

    __shared__ float s_red[4];
    if (lane == 0) s_red[wave] = res;
    __syncthreads();
    if (tid == 0)
        partials[blockIdx.x] = s_red[0] + s_red[1] + s_red[2] + s_red[3];
}

__global__ __launch_bounds__(256) void reduce_partials_kernel(
    const float* __restrict__ partials, int num_partials,
    float* __restrict__ out, float inv_n)
{
    const int tid  = threadIdx.x;
    const int lane = tid & 63;
    const int wave = tid >> 6;
    __shared__ float s_red[4];

    float acc = 0.0f;
    for (int i = tid; i < num_partials; i += 256)
        acc += partials[i];
    #pragma unroll
    for (int msk = 1; msk < 64; msk <<= 1)
        acc += __shfl_xor(acc, msk, 64);
    if (lane == 0) s_red[wave] = acc;
    __syncthreads();
    if (tid == 0)
        out[0] = (s_red[0] + s_red[1] + s_red[2] + s_red[3]) * inv_n;
}

extern "C" void kernel_launch(void* const* d_in, const int* in_sizes, int n_in,
                              void* d_out, int out_size, void* d_ws, size_t ws_size,
                              hipStream_t stream) {
    const float* features   = (const float*)d_in[0];
    const float* labels     = (const float*)d_in[1];
    const float* mean_class = (const float*)d_in[2];
    float* out = (float*)d_out;
    float* partials = (float*)d_ws;

    const int n_rows = in_sizes[0] / EMBED;          // 32768
    const int num_blocks = (n_rows + 3) / 4;         // 8192 -> 32 KB ws

    angular_rows_kernel<<<num_blocks, 256, 0, stream>>>(
        features, labels, mean_class, partials, n_rows);
    reduce_partials_kernel<<<1, 256, 0, stream>>>(
        partials, num_blocks, out, 1.0f / (float)n_rows);
}